// Round 2
// baseline (444.225 us; speedup 1.0000x reference)
//
#include <hip/hip_runtime.h>
#include <math.h>

#define C_   256
#define WH   4096

// ---------------- workspace layout (floats) ----------------
// qbn   : [16][16][4096]              @ 0          (1,048,576)
// kkbn  : [16][16][4096]              @ 1,048,576  (1,048,576)
// stats : [16][16][2]                 @ 2,097,152  (512)
// Wt    : [16][4096]                  @ 2,097,664  (65,536)
// Mpart : [16][32 part][32][256]      @ 2,163,200  (4,194,304)
//   (pstats [256 rows][16 chunk][2] aliases the first 8192 floats of Mpart:
//    written by proj, read by wtcomb, then overwritten by ut -> safe)
// lam   : [16][16][64]                @ 6,357,504  (16,384)

// ---- Wt (blocks 0..63) + softmax-stats combine (block 64) ----
__global__ __launch_bounds__(256) void wtcomb_kernel(const float* __restrict__ emb,
                                                     const float* __restrict__ pstats,
                                                     float* __restrict__ Wt,
                                                     float* __restrict__ stats)
{
    if (blockIdx.x == 64) {
        int row = threadIdx.x;           // 0..255 = b*16+hk
        const float* ps = pstats + (size_t)row * 32;
        float M = ps[0];
#pragma unroll
        for (int ch = 1; ch < 16; ++ch) M = fmaxf(M, ps[ch * 2]);
        float S = 0.f;
#pragma unroll
        for (int ch = 0; ch < 16; ++ch) S += ps[ch * 2 + 1] * __expf(ps[ch * 2] - M);
        stats[row * 2 + 0] = M;
        stats[row * 2 + 1] = 1.f / S;
        return;
    }
    int hk = blockIdx.x >> 2, quarter = blockIdx.x & 3;
    int h = hk >> 2, k = hk & 3;
    const float* e = emb + (size_t)(k * 4 + h) * 529;   // emb[k][h][0][0][i][j]
    __shared__ float colsum[23][64];
    for (int t = threadIdx.x; t < 23 * 64; t += 256) {
        int i = t / 64, q = t % 64;
        int jlo = max(0, q - 52), jhi = min(22, q + 11);
        float s = 0.f;
        for (int j = jlo; j <= jhi; ++j) s += e[i * 23 + j];
        colsum[i][q] = s;
    }
    __syncthreads();
    for (int tt = threadIdx.x; tt < 1024; tt += 256) {
        int t = quarter * 1024 + tt;
        int p = t >> 6, q = t & 63;
        int ilo = max(0, p - 52), ihi = min(22, p + 11);
        float s = 0.f;
        for (int i = ilo; i <= ihi; ++i) s += colsum[i][q];
        Wt[(size_t)hk * WH + t] = s;
    }
}

// ---- q/k 1x1 projections + BN + per-chunk softmax partials.
// 512 thr = 8 waves: waves 0..3 do q rows, 4..7 do k rows (4 rows each).
// Thread handles 4 px via float4. Weight reads are wave-uniform (scalar). ----
__global__ __launch_bounds__(512) void proj_kernel(
    const float* __restrict__ x,
    const float* __restrict__ qw, const float* __restrict__ kw,
    const float* __restrict__ qg, const float* __restrict__ qb,
    const float* __restrict__ qm, const float* __restrict__ qv,
    const float* __restrict__ kg, const float* __restrict__ kb,
    const float* __restrict__ km, const float* __restrict__ kv,
    float* __restrict__ qbn, float* __restrict__ kkbn, float* __restrict__ pstats)
{
    int t = threadIdx.x;
    int b = blockIdx.x >> 4, chunk = blockIdx.x & 15;
    int lane = t & 63;
    int og = __builtin_amdgcn_readfirstlane(t >> 6);   // 0..7, wave-uniform
    int isK = og >> 2;
    int o4 = (og & 3) * 4;
    int xy = chunk * 256 + lane * 4;

    const float* wsrc = isK ? kw : qw;
    const float* w0 = wsrc + (size_t)(o4 + 0) * 256;
    const float* w1 = wsrc + (size_t)(o4 + 1) * 256;
    const float* w2 = wsrc + (size_t)(o4 + 2) * 256;
    const float* w3 = wsrc + (size_t)(o4 + 3) * 256;

    float4 a0 = {0,0,0,0}, a1 = {0,0,0,0}, a2 = {0,0,0,0}, a3 = {0,0,0,0};
    const float* xb = x + (size_t)b * C_ * WH + xy;
#pragma unroll 8
    for (int c = 0; c < 256; ++c) {
        float4 xv = *(const float4*)(xb + (size_t)c * WH);
        float f0 = w0[c], f1 = w1[c], f2 = w2[c], f3 = w3[c];
        a0.x += xv.x*f0; a0.y += xv.y*f0; a0.z += xv.z*f0; a0.w += xv.w*f0;
        a1.x += xv.x*f1; a1.y += xv.y*f1; a1.z += xv.z*f1; a1.w += xv.w*f1;
        a2.x += xv.x*f2; a2.y += xv.y*f2; a2.z += xv.z*f2; a2.w += xv.w*f2;
        a3.x += xv.x*f3; a3.y += xv.y*f3; a3.z += xv.z*f3; a3.w += xv.w*f3;
    }
    float4 acc4[4] = {a0, a1, a2, a3};

    if (!isK) {
#pragma unroll
        for (int i = 0; i < 4; ++i) {
            int hk = o4 + i;
            float s  = qg[hk] * rsqrtf(qv[hk] + 1e-5f);
            float tq = qb[hk] - qm[hk] * s;
            float4 a = acc4[i], o;
            o.x = a.x * s + tq; o.y = a.y * s + tq;
            o.z = a.z * s + tq; o.w = a.w * s + tq;
            *(float4*)(qbn + ((size_t)b * 16 + hk) * WH + xy) = o;
        }
    } else {
#pragma unroll
        for (int i = 0; i < 4; ++i) {
            int hk = o4 + i;
            float s2 = kg[hk] * rsqrtf(kv[hk] + 1e-5f);
            float tk = kb[hk] - km[hk] * s2;
            float4 a = acc4[i], o;
            o.x = a.x * s2 + tk; o.y = a.y * s2 + tk;
            o.z = a.z * s2 + tk; o.w = a.w * s2 + tk;
            *(float4*)(kkbn + ((size_t)b * 16 + hk) * WH + xy) = o;
            // per-chunk softmax partials: wave = chunk (64 lanes x 4 px = 256 px)
            float m = fmaxf(fmaxf(o.x, o.y), fmaxf(o.z, o.w));
#pragma unroll
            for (int off = 32; off; off >>= 1) m = fmaxf(m, __shfl_xor(m, off, 64));
            float e = __expf(o.x - m) + __expf(o.y - m) + __expf(o.z - m) + __expf(o.w - m);
#pragma unroll
            for (int off = 32; off; off >>= 1) e += __shfl_xor(e, off, 64);
            if (lane == 0) {
                float* ps = pstats + ((size_t)(b * 16 + hk) * 16 + chunk) * 2;
                ps[0] = m; ps[1] = e;
            }
        }
    }
}

// ---- U/T contractions. Grid 512 = (b, seg, half). 256 thr = 4 waves.
// Thread: 4 c's (cq + 64j) x 8 rows (4 U + 4 T), acc[8][4] = 32 VGPR.
// rgrp = t>>6 is wave-uniform -> all w reads are LDS broadcasts.
// x staged per 32-xy tile, single-buffered (round-0 proven pattern);
// stride-36 float4 reads tile all 32 banks -> conflict-free. ----
__global__ __launch_bounds__(256, 2) void ut_kernel(
    const float* __restrict__ x, const float* __restrict__ kkbn,
    const float* __restrict__ stats, const float* __restrict__ Wt,
    float* __restrict__ Mpart)
{
    __shared__ __align__(16) float xls[256][36];   // 36,864 B
    __shared__ __align__(16) float wls[32][132];   // 16,896 B  (53.8 KB total -> 2 blk/CU)
    int t = threadIdx.x;
    int b = blockIdx.x >> 5;
    int seg = (blockIdx.x >> 1) & 15;
    int half = blockIdx.x & 1;
    int xys0 = seg * 256 + half * 128;

    // ---- stage w rows (sm for r<16, Wt for r>=16): 32 rows x 128 xy ----
    {
        int r = t >> 3;              // 0..31
        int xo = (t & 7) * 16;       // 16 xy per thread
        if (r < 16) {
            float mm  = stats[(b * 16 + r) * 2 + 0];
            float inv = stats[(b * 16 + r) * 2 + 1];
            const float* src = kkbn + ((size_t)b * 16 + r) * WH + xys0 + xo;
#pragma unroll
            for (int j = 0; j < 16; j += 4) {
                float4 v = *(const float4*)(src + j);
                wls[r][xo + j + 0] = __expf(v.x - mm) * inv;
                wls[r][xo + j + 1] = __expf(v.y - mm) * inv;
                wls[r][xo + j + 2] = __expf(v.z - mm) * inv;
                wls[r][xo + j + 3] = __expf(v.w - mm) * inv;
            }
        } else {
            const float* src = Wt + (size_t)(r - 16) * WH + xys0 + xo;
#pragma unroll
            for (int j = 0; j < 16; j += 4)
                *(float4*)&wls[r][xo + j] = *(const float4*)(src + j);
        }
    }

    int cq = t & 63;                 // c's: cq, cq+64, cq+128, cq+192
    int rgrp = t >> 6;               // 0..3, wave-uniform
    const float* xbase = x + (size_t)b * C_ * WH + xys0;

    float acc[8][4] = {};
    for (int sub = 0; sub < 4; ++sub) {
        __syncthreads();
        // stage x: 256 c x 32 xy (32 KB), 8 float4 per thread, coalesced
#pragma unroll
        for (int i = 0; i < 8; ++i) {
            int id = t + i * 256;
            int c = id >> 3, j = (id & 7) * 4;
            *(float4*)&xls[c][j] = *(const float4*)(xbase + (size_t)c * WH + sub * 32 + j);
        }
        __syncthreads();
#pragma unroll
        for (int q = 0; q < 8; ++q) {
            float4 x0 = *(const float4*)&xls[cq      ][q * 4];
            float4 x1 = *(const float4*)&xls[cq +  64][q * 4];
            float4 x2 = *(const float4*)&xls[cq + 128][q * 4];
            float4 x3 = *(const float4*)&xls[cq + 192][q * 4];
#pragma unroll
            for (int rr = 0; rr < 8; ++rr) {
                int row = (rr < 4) ? (rgrp * 4 + rr) : (16 + rgrp * 4 + rr - 4);
                float4 w4 = *(const float4*)&wls[row][sub * 32 + q * 4];  // broadcast
                acc[rr][0] += x0.x*w4.x + x0.y*w4.y + x0.z*w4.z + x0.w*w4.w;
                acc[rr][1] += x1.x*w4.x + x1.y*w4.y + x1.z*w4.z + x1.w*w4.w;
                acc[rr][2] += x2.x*w4.x + x2.y*w4.y + x2.z*w4.z + x2.w*w4.w;
                acc[rr][3] += x3.x*w4.x + x3.y*w4.y + x3.z*w4.z + x3.w*w4.w;
            }
        }
    }

    float* mp = Mpart + (((size_t)b * 16 + seg) * 2 + half) * 8192;
#pragma unroll
    for (int rr = 0; rr < 8; ++rr) {
        int row = (rr < 4) ? (rgrp * 4 + rr) : (16 + rgrp * 4 + rr - 4);
        mp[row * 256 + cq      ] = acc[rr][0];
        mp[row * 256 + cq +  64] = acc[rr][1];
        mp[row * 256 + cq + 128] = acc[rr][2];
        mp[row * 256 + cq + 192] = acc[rr][3];
    }
}

// ---- lambda[b,hk,v] = sum_c v_w[h,v,c] * (U+T)[b,hk,c]. One block per (b,hk). ----
__global__ __launch_bounds__(256) void lam_kernel(
    const float* __restrict__ Mpart, const float* __restrict__ vw,
    float* __restrict__ lam)
{
    __shared__ float msum[256];
    __shared__ float vls[64][68];
    __shared__ float psum[4][64];
    int t = threadIdx.x;
    int b = blockIdx.x >> 4, hk = blockIdx.x & 15, h = hk >> 2;

    {
        const float* mp = Mpart + (size_t)b * 32 * 8192 + t;
        float s = 0.f;
        for (int seg = 0; seg < 32; ++seg) {
            const float* m2 = mp + (size_t)seg * 8192;
            s += m2[hk * 256] + m2[(16 + hk) * 256];
        }
        msum[t] = s;
    }

    int v = t & 63, cq = t >> 6;
    float acc = 0.f;
    const float* vwh = vw + (size_t)h * 64 * 256;
    for (int ch = 0; ch < 4; ++ch) {
        __syncthreads();
#pragma unroll
        for (int k = 0; k < 4; ++k) {
            int e = t + k * 256;
            int vv = e >> 4, c4 = (e & 15) * 4;
            *(float4*)&vls[vv][c4] = *(const float4*)(vwh + (size_t)vv * 256 + ch * 64 + c4);
        }
        __syncthreads();
#pragma unroll
        for (int i4 = 0; i4 < 4; ++i4) {
            float4 a  = *(const float4*)&vls[v][cq * 16 + i4 * 4];
            float4 m4 = *(const float4*)&msum[ch * 64 + cq * 16 + i4 * 4];
            acc += a.x * m4.x + a.y * m4.y + a.z * m4.z + a.w * m4.w;
        }
    }
    psum[cq][v] = acc;
    __syncthreads();
    if (t < 64)
        lam[((size_t)b * 16 + hk) * 64 + t] =
            psum[0][t] + psum[1][t] + psum[2][t] + psum[3][t];
}

// ---- out[b, h*64+v, xy] = sum_k qbn[b,hk,xy] * lam[b,hk,v].
// Block = (b, h, xy-quarter); thread = xy-quad (float4 loads/stores);
// lam reads wave-uniform (scalar). ----
__global__ __launch_bounds__(256) void out_kernel(
    const float* __restrict__ qbn, const float* __restrict__ lam,
    float* __restrict__ out)
{
    int t = threadIdx.x;
    int b = blockIdx.x >> 4, s = blockIdx.x & 15;
    int h = s >> 2, qc = s & 3;
    int xy = qc * 1024 + t * 4;
    float4 q0 = *(const float4*)(qbn + ((size_t)b * 16 + h * 4 + 0) * WH + xy);
    float4 q1 = *(const float4*)(qbn + ((size_t)b * 16 + h * 4 + 1) * WH + xy);
    float4 q2 = *(const float4*)(qbn + ((size_t)b * 16 + h * 4 + 2) * WH + xy);
    float4 q3 = *(const float4*)(qbn + ((size_t)b * 16 + h * 4 + 3) * WH + xy);
    const float* lb = lam + (size_t)b * 1024 + (size_t)h * 256;
    float* ob = out + ((size_t)b * 256 + (size_t)h * 64) * WH + xy;
#pragma unroll 8
    for (int v = 0; v < 64; ++v) {
        float l0 = lb[v], l1 = lb[64 + v], l2 = lb[128 + v], l3 = lb[192 + v];
        float4 o;
        o.x = q0.x*l0 + q1.x*l1 + q2.x*l2 + q3.x*l3;
        o.y = q0.y*l0 + q1.y*l1 + q2.y*l2 + q3.y*l3;
        o.z = q0.z*l0 + q1.z*l1 + q2.z*l2 + q3.z*l3;
        o.w = q0.w*l0 + q1.w*l1 + q2.w*l2 + q3.w*l3;
        *(float4*)(ob + (size_t)v * WH) = o;
    }
}

extern "C" void kernel_launch(void* const* d_in, const int* in_sizes, int n_in,
                              void* d_out, int out_size, void* d_ws, size_t ws_size,
                              hipStream_t stream)
{
    const float* x   = (const float*)d_in[0];
    const float* qw  = (const float*)d_in[1];
    const float* qg  = (const float*)d_in[2];
    const float* qb  = (const float*)d_in[3];
    const float* qm  = (const float*)d_in[4];
    const float* qv  = (const float*)d_in[5];
    const float* kw  = (const float*)d_in[6];
    const float* kg  = (const float*)d_in[7];
    const float* kb  = (const float*)d_in[8];
    const float* km  = (const float*)d_in[9];
    const float* kv  = (const float*)d_in[10];
    const float* vw  = (const float*)d_in[11];
    const float* emb = (const float*)d_in[12];

    float* ws    = (float*)d_ws;
    float* qbn   = ws;
    float* kkbn  = ws + 1048576;
    float* stats = ws + 2097152;
    float* Wt    = ws + 2097664;
    float* Mpart = ws + 2163200;
    float* pstats = Mpart;            // alias: proj writes, wtcomb reads, ut overwrites
    float* lam   = ws + 6357504;
    float* out   = (float*)d_out;

    hipLaunchKernelGGL(proj_kernel,  dim3(256), dim3(512), 0, stream,
                       x, qw, kw, qg, qb, qm, qv, kg, kb, km, kv, qbn, kkbn, pstats);
    hipLaunchKernelGGL(wtcomb_kernel, dim3(65), dim3(256), 0, stream, emb, pstats, Wt, stats);
    hipLaunchKernelGGL(ut_kernel,    dim3(512), dim3(256), 0, stream,
                       x, kkbn, stats, Wt, Mpart);
    hipLaunchKernelGGL(lam_kernel,   dim3(256), dim3(256), 0, stream, Mpart, vw, lam);
    hipLaunchKernelGGL(out_kernel,   dim3(256), dim3(256), 0, stream, qbn, lam, out);
}

// Round 3
// 97.176 us; speedup vs baseline: 4.5713x; 4.5713x over previous
//
#include <hip/hip_runtime.h>
#include <math.h>

#define C_   256
#define WH   4096

// ---------------- workspace layout (floats) ----------------
// qbn   : [16][16][4096]          @ 0          (1,048,576)
// kkbn  : [16][16][4096]          @ 1,048,576  (1,048,576)
// stats : [16][16][2]             @ 2,097,152  (512)
// Wt    : [16][4096]              @ 2,097,664  (65,536)
// Mpart : [16][16 seg][32][256]   @ 2,163,200  (2,097,152)
//   (pstats [256 rows][16 chunk][2] aliases the first 8192 floats of Mpart:
//    written by proj, read by wtcomb, then overwritten by ut -> safe)
// lam   : [16][16][64]            @ 4,260,352  (16,384)

// ---- Wt (blocks 0..63) + softmax-stats combine (block 64) ----
__global__ __launch_bounds__(256) void wtcomb_kernel(const float* __restrict__ emb,
                                                     const float* __restrict__ pstats,
                                                     float* __restrict__ Wt,
                                                     float* __restrict__ stats)
{
    if (blockIdx.x == 64) {
        int row = threadIdx.x;           // 0..255 = b*16+hk
        const float* ps = pstats + (size_t)row * 32;
        float M = ps[0];
#pragma unroll
        for (int ch = 1; ch < 16; ++ch) M = fmaxf(M, ps[ch * 2]);
        float S = 0.f;
#pragma unroll
        for (int ch = 0; ch < 16; ++ch) S += ps[ch * 2 + 1] * __expf(ps[ch * 2] - M);
        stats[row * 2 + 0] = M;
        stats[row * 2 + 1] = 1.f / S;
        return;
    }
    int hk = blockIdx.x >> 2, quarter = blockIdx.x & 3;
    int h = hk >> 2, k = hk & 3;
    const float* e = emb + (size_t)(k * 4 + h) * 529;   // emb[k][h][0][0][i][j]
    __shared__ float colsum[23][64];
    for (int t = threadIdx.x; t < 23 * 64; t += 256) {
        int i = t / 64, q = t % 64;
        int jlo = max(0, q - 52), jhi = min(22, q + 11);
        float s = 0.f;
        for (int j = jlo; j <= jhi; ++j) s += e[i * 23 + j];
        colsum[i][q] = s;
    }
    __syncthreads();
    for (int tt = threadIdx.x; tt < 1024; tt += 256) {
        int t = quarter * 1024 + tt;
        int p = t >> 6, q = t & 63;
        int ilo = max(0, p - 52), ihi = min(22, p + 11);
        float s = 0.f;
        for (int i = ilo; i <= ihi; ++i) s += colsum[i][q];
        Wt[(size_t)hk * WH + t] = s;
    }
}

// ---- q/k 1x1 projections + BN + per-chunk softmax partials.
// 512 thr = 8 waves: waves 0..3 do q rows, 4..7 do k rows (4 rows each).
// Thread handles 4 px via float4. Weight reads are wave-uniform (scalar). ----
__global__ __launch_bounds__(512) void proj_kernel(
    const float* __restrict__ x,
    const float* __restrict__ qw, const float* __restrict__ kw,
    const float* __restrict__ qg, const float* __restrict__ qb,
    const float* __restrict__ qm, const float* __restrict__ qv,
    const float* __restrict__ kg, const float* __restrict__ kb,
    const float* __restrict__ km, const float* __restrict__ kv,
    float* __restrict__ qbn, float* __restrict__ kkbn, float* __restrict__ pstats)
{
    int t = threadIdx.x;
    int b = blockIdx.x >> 4, chunk = blockIdx.x & 15;
    int lane = t & 63;
    int og = __builtin_amdgcn_readfirstlane(t >> 6);   // 0..7, wave-uniform
    int isK = og >> 2;
    int o4 = (og & 3) * 4;
    int xy = chunk * 256 + lane * 4;

    const float* wsrc = isK ? kw : qw;
    const float* w0 = wsrc + (size_t)(o4 + 0) * 256;
    const float* w1 = wsrc + (size_t)(o4 + 1) * 256;
    const float* w2 = wsrc + (size_t)(o4 + 2) * 256;
    const float* w3 = wsrc + (size_t)(o4 + 3) * 256;

    float4 a0 = {0,0,0,0}, a1 = {0,0,0,0}, a2 = {0,0,0,0}, a3 = {0,0,0,0};
    const float* xb = x + (size_t)b * C_ * WH + xy;
#pragma unroll 8
    for (int c = 0; c < 256; ++c) {
        float4 xv = *(const float4*)(xb + (size_t)c * WH);
        float f0 = w0[c], f1 = w1[c], f2 = w2[c], f3 = w3[c];
        a0.x += xv.x*f0; a0.y += xv.y*f0; a0.z += xv.z*f0; a0.w += xv.w*f0;
        a1.x += xv.x*f1; a1.y += xv.y*f1; a1.z += xv.z*f1; a1.w += xv.w*f1;
        a2.x += xv.x*f2; a2.y += xv.y*f2; a2.z += xv.z*f2; a2.w += xv.w*f2;
        a3.x += xv.x*f3; a3.y += xv.y*f3; a3.z += xv.z*f3; a3.w += xv.w*f3;
    }
    float4 acc4[4] = {a0, a1, a2, a3};

    if (!isK) {
#pragma unroll
        for (int i = 0; i < 4; ++i) {
            int hk = o4 + i;
            float s  = qg[hk] * rsqrtf(qv[hk] + 1e-5f);
            float tq = qb[hk] - qm[hk] * s;
            float4 a = acc4[i], o;
            o.x = a.x * s + tq; o.y = a.y * s + tq;
            o.z = a.z * s + tq; o.w = a.w * s + tq;
            *(float4*)(qbn + ((size_t)b * 16 + hk) * WH + xy) = o;
        }
    } else {
#pragma unroll
        for (int i = 0; i < 4; ++i) {
            int hk = o4 + i;
            float s2 = kg[hk] * rsqrtf(kv[hk] + 1e-5f);
            float tk = kb[hk] - km[hk] * s2;
            float4 a = acc4[i], o;
            o.x = a.x * s2 + tk; o.y = a.y * s2 + tk;
            o.z = a.z * s2 + tk; o.w = a.w * s2 + tk;
            *(float4*)(kkbn + ((size_t)b * 16 + hk) * WH + xy) = o;
            // per-chunk softmax partials: wave = chunk (64 lanes x 4 px = 256 px)
            float m = fmaxf(fmaxf(o.x, o.y), fmaxf(o.z, o.w));
#pragma unroll
            for (int off = 32; off; off >>= 1) m = fmaxf(m, __shfl_xor(m, off, 64));
            float e = __expf(o.x - m) + __expf(o.y - m) + __expf(o.z - m) + __expf(o.w - m);
#pragma unroll
            for (int off = 32; off; off >>= 1) e += __shfl_xor(e, off, 64);
            if (lane == 0) {
                float* ps = pstats + ((size_t)(b * 16 + hk) * 16 + chunk) * 2;
                ps[0] = m; ps[1] = e;
            }
        }
    }
}

// ---- U/T contractions. 1024 thr: thread = (c-pair, 4-row group), acc[2][4].
// ROUND-0 PROVEN VERSION (no spill): small unroll window, acc[2][4]. ----
__global__ __launch_bounds__(1024) void ut_kernel(
    const float* __restrict__ x, const float* __restrict__ kkbn,
    const float* __restrict__ stats, const float* __restrict__ Wt,
    float* __restrict__ Mpart)
{
    __shared__ float xls[256][36];   // [c][xy], stride 36 floats
    __shared__ float wls[32][36];    // [xy][r], padded
    __shared__ float st[32];
    int t = threadIdx.x;
    int b = blockIdx.x >> 4, seg = blockIdx.x & 15;
    int cidx = t & 127;              // c-pair: cidx, cidx+128
    int rg = t >> 7;                 // 8 groups of 4 rows
    if (t < 32) st[t] = stats[(b * 16 + (t >> 1)) * 2 + (t & 1)];

    float acc[2][4] = {{0.f,0.f,0.f,0.f},{0.f,0.f,0.f,0.f}};
    const float* xb = x + (size_t)b * C_ * WH;
    int sc = t >> 3, sj4 = (t & 7) * 4;   // staging: rows sc, sc+128
    int srr = t >> 5, sxy = t & 31;       // w staging coords

    for (int sub = 0; sub < 8; ++sub) {
        int xys = seg * 256 + sub * 32;
        __syncthreads();
        {   // stage x[256 c][32 xy]
            const float* xp = xb + xys + sj4;
            float4 v0 = *(const float4*)(xp + (size_t)sc * WH);
            float4 v1 = *(const float4*)(xp + (size_t)(sc + 128) * WH);
            *(float4*)&xls[sc][sj4] = v0;
            *(float4*)&xls[sc + 128][sj4] = v1;
        }
        {   // stage row weights: sm (rows 0..15), Wt (rows 16..31)
            float val;
            if (srr < 16) {
                float kkv = kkbn[((size_t)b * 16 + srr) * WH + xys + sxy];
                val = __expf(kkv - st[2 * srr]) * st[2 * srr + 1];
            } else {
                val = Wt[(size_t)(srr - 16) * WH + xys + sxy];
            }
            wls[sxy][srr] = val;
        }
        __syncthreads();
#pragma unroll
        for (int j4 = 0; j4 < 32; j4 += 4) {
            float4 xa = *(const float4*)&xls[cidx][j4];
            float4 xc = *(const float4*)&xls[cidx + 128][j4];
            float4 w0 = *(const float4*)&wls[j4 + 0][rg * 4];
            float4 w1 = *(const float4*)&wls[j4 + 1][rg * 4];
            float4 w2 = *(const float4*)&wls[j4 + 2][rg * 4];
            float4 w3 = *(const float4*)&wls[j4 + 3][rg * 4];
            acc[0][0] += xa.x*w0.x + xa.y*w1.x + xa.z*w2.x + xa.w*w3.x;
            acc[0][1] += xa.x*w0.y + xa.y*w1.y + xa.z*w2.y + xa.w*w3.y;
            acc[0][2] += xa.x*w0.z + xa.y*w1.z + xa.z*w2.z + xa.w*w3.z;
            acc[0][3] += xa.x*w0.w + xa.y*w1.w + xa.z*w2.w + xa.w*w3.w;
            acc[1][0] += xc.x*w0.x + xc.y*w1.x + xc.z*w2.x + xc.w*w3.x;
            acc[1][1] += xc.x*w0.y + xc.y*w1.y + xc.z*w2.y + xc.w*w3.y;
            acc[1][2] += xc.x*w0.z + xc.y*w1.z + xc.z*w2.z + xc.w*w3.z;
            acc[1][3] += xc.x*w0.w + xc.y*w1.w + xc.z*w2.w + xc.w*w3.w;
        }
    }
    float* mp = Mpart + (size_t)(b * 16 + seg) * 32 * 256;
#pragma unroll
    for (int r = 0; r < 4; ++r) {
        mp[(rg * 4 + r) * 256 + cidx]       = acc[0][r];
        mp[(rg * 4 + r) * 256 + cidx + 128] = acc[1][r];
    }
}

// ---- lambda[b,hk,v] = sum_c v_w[h,v,c] * (U+T)[b,hk,c]. One block per (b,hk). ----
__global__ __launch_bounds__(256) void lam_kernel(
    const float* __restrict__ Mpart, const float* __restrict__ vw,
    float* __restrict__ lam)
{
    __shared__ float msum[256];
    __shared__ float vls[64][68];
    __shared__ float psum[4][64];
    int t = threadIdx.x;
    int b = blockIdx.x >> 4, hk = blockIdx.x & 15, h = hk >> 2;

    {
        const float* mp = Mpart + (size_t)b * 16 * 8192 + t;
        float s = 0.f;
        for (int seg = 0; seg < 16; ++seg) {
            const float* m2 = mp + (size_t)seg * 8192;
            s += m2[hk * 256] + m2[(16 + hk) * 256];
        }
        msum[t] = s;
    }

    int v = t & 63, cq = t >> 6;
    float acc = 0.f;
    const float* vwh = vw + (size_t)h * 64 * 256;
    for (int ch = 0; ch < 4; ++ch) {
        __syncthreads();
#pragma unroll
        for (int k = 0; k < 4; ++k) {
            int e = t + k * 256;
            int vv = e >> 4, c4 = (e & 15) * 4;
            *(float4*)&vls[vv][c4] = *(const float4*)(vwh + (size_t)vv * 256 + ch * 64 + c4);
        }
        __syncthreads();
#pragma unroll
        for (int i4 = 0; i4 < 4; ++i4) {
            float4 a  = *(const float4*)&vls[v][cq * 16 + i4 * 4];
            float4 m4 = *(const float4*)&msum[ch * 64 + cq * 16 + i4 * 4];
            acc += a.x * m4.x + a.y * m4.y + a.z * m4.z + a.w * m4.w;
        }
    }
    psum[cq][v] = acc;
    __syncthreads();
    if (t < 64)
        lam[((size_t)b * 16 + hk) * 64 + t] =
            psum[0][t] + psum[1][t] + psum[2][t] + psum[3][t];
}

// ---- out[b, h*64+v, xy] = sum_k qbn[b,hk,xy] * lam[b,hk,v].
// Block = (b, h, xy-quarter); thread = xy-quad (float4 loads/stores);
// lam reads wave-uniform (scalar). ----
__global__ __launch_bounds__(256) void out_kernel(
    const float* __restrict__ qbn, const float* __restrict__ lam,
    float* __restrict__ out)
{
    int t = threadIdx.x;
    int b = blockIdx.x >> 4, s = blockIdx.x & 15;
    int h = s >> 2, qc = s & 3;
    int xy = qc * 1024 + t * 4;
    float4 q0 = *(const float4*)(qbn + ((size_t)b * 16 + h * 4 + 0) * WH + xy);
    float4 q1 = *(const float4*)(qbn + ((size_t)b * 16 + h * 4 + 1) * WH + xy);
    float4 q2 = *(const float4*)(qbn + ((size_t)b * 16 + h * 4 + 2) * WH + xy);
    float4 q3 = *(const float4*)(qbn + ((size_t)b * 16 + h * 4 + 3) * WH + xy);
    const float* lb = lam + (size_t)b * 1024 + (size_t)h * 256;
    float* ob = out + ((size_t)b * 256 + (size_t)h * 64) * WH + xy;
#pragma unroll 8
    for (int v = 0; v < 64; ++v) {
        float l0 = lb[v], l1 = lb[64 + v], l2 = lb[128 + v], l3 = lb[192 + v];
        float4 o;
        o.x = q0.x*l0 + q1.x*l1 + q2.x*l2 + q3.x*l3;
        o.y = q0.y*l0 + q1.y*l1 + q2.y*l2 + q3.y*l3;
        o.z = q0.z*l0 + q1.z*l1 + q2.z*l2 + q3.z*l3;
        o.w = q0.w*l0 + q1.w*l1 + q2.w*l2 + q3.w*l3;
        *(float4*)(ob + (size_t)v * WH) = o;
    }
}

extern "C" void kernel_launch(void* const* d_in, const int* in_sizes, int n_in,
                              void* d_out, int out_size, void* d_ws, size_t ws_size,
                              hipStream_t stream)
{
    const float* x   = (const float*)d_in[0];
    const float* qw  = (const float*)d_in[1];
    const float* qg  = (const float*)d_in[2];
    const float* qb  = (const float*)d_in[3];
    const float* qm  = (const float*)d_in[4];
    const float* qv  = (const float*)d_in[5];
    const float* kw  = (const float*)d_in[6];
    const float* kg  = (const float*)d_in[7];
    const float* kb  = (const float*)d_in[8];
    const float* km  = (const float*)d_in[9];
    const float* kv  = (const float*)d_in[10];
    const float* vw  = (const float*)d_in[11];
    const float* emb = (const float*)d_in[12];

    float* ws    = (float*)d_ws;
    float* qbn   = ws;
    float* kkbn  = ws + 1048576;
    float* stats = ws + 2097152;
    float* Wt    = ws + 2097664;
    float* Mpart = ws + 2163200;
    float* pstats = Mpart;            // alias: proj writes, wtcomb reads, ut overwrites
    float* lam   = ws + 4260352;
    float* out   = (float*)d_out;

    hipLaunchKernelGGL(proj_kernel,  dim3(256), dim3(512), 0, stream,
                       x, qw, kw, qg, qb, qm, qv, kg, kb, km, kv, qbn, kkbn, pstats);
    hipLaunchKernelGGL(wtcomb_kernel, dim3(65), dim3(256), 0, stream, emb, pstats, Wt, stats);
    hipLaunchKernelGGL(ut_kernel,    dim3(256), dim3(1024), 0, stream,
                       x, kkbn, stats, Wt, Mpart);
    hipLaunchKernelGGL(lam_kernel,   dim3(256), dim3(256), 0, stream, Mpart, vw, lam);
    hipLaunchKernelGGL(out_kernel,   dim3(256), dim3(256), 0, stream, qbn, lam, out);
}

// Round 4
// 86.669 us; speedup vs baseline: 5.1255x; 1.1212x over previous
//
#include <hip/hip_runtime.h>
#include <math.h>

#define C_   256
#define WH   4096

typedef _Float16 f16x8 __attribute__((ext_vector_type(8)));
typedef float    f32x4 __attribute__((ext_vector_type(4)));

// ---------------- workspace layout (floats) ----------------
// qbn   : [16][16][4096]          @ 0          (1,048,576)
// kkbn  : [16][16][4096]          @ 1,048,576  (1,048,576)
// stats : [16][16][2]             @ 2,097,152  (512)
// Wt    : [16][4096]              @ 2,097,664  (65,536)
// Mpart : [16][16 seg][32][256]   @ 2,163,200  (2,097,152)
//   (pstats [256 rows][16 chunk][2] aliases the first 8192 floats of Mpart:
//    written by proj, read by wtcomb, then overwritten by ut -> safe)
// lam   : [16][16][64]            @ 4,260,352  (16,384)

// ---- Wt (blocks 0..63) + softmax-stats combine (block 64) ----
__global__ __launch_bounds__(256) void wtcomb_kernel(const float* __restrict__ emb,
                                                     const float* __restrict__ pstats,
                                                     float* __restrict__ Wt,
                                                     float* __restrict__ stats)
{
    if (blockIdx.x == 64) {
        int row = threadIdx.x;           // 0..255 = b*16+hk
        const float* ps = pstats + (size_t)row * 32;
        float M = ps[0];
#pragma unroll
        for (int ch = 1; ch < 16; ++ch) M = fmaxf(M, ps[ch * 2]);
        float S = 0.f;
#pragma unroll
        for (int ch = 0; ch < 16; ++ch) S += ps[ch * 2 + 1] * __expf(ps[ch * 2] - M);
        stats[row * 2 + 0] = M;
        stats[row * 2 + 1] = 1.f / S;
        return;
    }
    int hk = blockIdx.x >> 2, quarter = blockIdx.x & 3;
    int h = hk >> 2, k = hk & 3;
    const float* e = emb + (size_t)(k * 4 + h) * 529;   // emb[k][h][0][0][i][j]
    __shared__ float colsum[23][64];
    for (int t = threadIdx.x; t < 23 * 64; t += 256) {
        int i = t / 64, q = t % 64;
        int jlo = max(0, q - 52), jhi = min(22, q + 11);
        float s = 0.f;
        for (int j = jlo; j <= jhi; ++j) s += e[i * 23 + j];
        colsum[i][q] = s;
    }
    __syncthreads();
    for (int tt = threadIdx.x; tt < 1024; tt += 256) {
        int t = quarter * 1024 + tt;
        int p = t >> 6, q = t & 63;
        int ilo = max(0, p - 52), ihi = min(22, p + 11);
        float s = 0.f;
        for (int i = ilo; i <= ihi; ++i) s += colsum[i][q];
        Wt[(size_t)hk * WH + t] = s;
    }
}

// ---- q/k 1x1 projections + BN + per-chunk softmax partials. ----
__global__ __launch_bounds__(512) void proj_kernel(
    const float* __restrict__ x,
    const float* __restrict__ qw, const float* __restrict__ kw,
    const float* __restrict__ qg, const float* __restrict__ qb,
    const float* __restrict__ qm, const float* __restrict__ qv,
    const float* __restrict__ kg, const float* __restrict__ kb,
    const float* __restrict__ km, const float* __restrict__ kv,
    float* __restrict__ qbn, float* __restrict__ kkbn, float* __restrict__ pstats)
{
    int t = threadIdx.x;
    int b = blockIdx.x >> 4, chunk = blockIdx.x & 15;
    int lane = t & 63;
    int og = __builtin_amdgcn_readfirstlane(t >> 6);   // 0..7, wave-uniform
    int isK = og >> 2;
    int o4 = (og & 3) * 4;
    int xy = chunk * 256 + lane * 4;

    const float* wsrc = isK ? kw : qw;
    const float* w0 = wsrc + (size_t)(o4 + 0) * 256;
    const float* w1 = wsrc + (size_t)(o4 + 1) * 256;
    const float* w2 = wsrc + (size_t)(o4 + 2) * 256;
    const float* w3 = wsrc + (size_t)(o4 + 3) * 256;

    float4 a0 = {0,0,0,0}, a1 = {0,0,0,0}, a2 = {0,0,0,0}, a3 = {0,0,0,0};
    const float* xb = x + (size_t)b * C_ * WH + xy;
#pragma unroll 8
    for (int c = 0; c < 256; ++c) {
        float4 xv = *(const float4*)(xb + (size_t)c * WH);
        float f0 = w0[c], f1 = w1[c], f2 = w2[c], f3 = w3[c];
        a0.x += xv.x*f0; a0.y += xv.y*f0; a0.z += xv.z*f0; a0.w += xv.w*f0;
        a1.x += xv.x*f1; a1.y += xv.y*f1; a1.z += xv.z*f1; a1.w += xv.w*f1;
        a2.x += xv.x*f2; a2.y += xv.y*f2; a2.z += xv.z*f2; a2.w += xv.w*f2;
        a3.x += xv.x*f3; a3.y += xv.y*f3; a3.z += xv.z*f3; a3.w += xv.w*f3;
    }
    float4 acc4[4] = {a0, a1, a2, a3};

    if (!isK) {
#pragma unroll
        for (int i = 0; i < 4; ++i) {
            int hk = o4 + i;
            float s  = qg[hk] * rsqrtf(qv[hk] + 1e-5f);
            float tq = qb[hk] - qm[hk] * s;
            float4 a = acc4[i], o;
            o.x = a.x * s + tq; o.y = a.y * s + tq;
            o.z = a.z * s + tq; o.w = a.w * s + tq;
            *(float4*)(qbn + ((size_t)b * 16 + hk) * WH + xy) = o;
        }
    } else {
#pragma unroll
        for (int i = 0; i < 4; ++i) {
            int hk = o4 + i;
            float s2 = kg[hk] * rsqrtf(kv[hk] + 1e-5f);
            float tk = kb[hk] - km[hk] * s2;
            float4 a = acc4[i], o;
            o.x = a.x * s2 + tk; o.y = a.y * s2 + tk;
            o.z = a.z * s2 + tk; o.w = a.w * s2 + tk;
            *(float4*)(kkbn + ((size_t)b * 16 + hk) * WH + xy) = o;
            float m = fmaxf(fmaxf(o.x, o.y), fmaxf(o.z, o.w));
#pragma unroll
            for (int off = 32; off; off >>= 1) m = fmaxf(m, __shfl_xor(m, off, 64));
            float e = __expf(o.x - m) + __expf(o.y - m) + __expf(o.z - m) + __expf(o.w - m);
#pragma unroll
            for (int off = 32; off; off >>= 1) e += __shfl_xor(e, off, 64);
            if (lane == 0) {
                float* ps = pstats + ((size_t)(b * 16 + hk) * 16 + chunk) * 2;
                ps[0] = m; ps[1] = e;
            }
        }
    }
}

// ---- U/T contractions via fp16 MFMA (fp32 accumulate).
// Per block (b,seg): D[32 r][256 c] = sum_{xy in seg} W[r][xy] * X[c][xy].
// mfma_f32_16x16x32_f16: A = W rows (M=32 -> 2 tiles), B = X^T (N=256 -> 16
// tiles, wave wid owns cols wid*32..+31), K = 256 (4 chunks x 64).
// Both A and B frags load as: lane -> row (l&15), 8 contig k at (l>>4)*8.
// LDS rows stride 72 f16 (144 B) -> frag reads & staging writes land exactly
// 8 lanes/bank-quad (the b128 floor). ----
__global__ __launch_bounds__(512) void ut_kernel(
    const float* __restrict__ x, const float* __restrict__ kkbn,
    const float* __restrict__ stats, const float* __restrict__ Wt,
    float* __restrict__ Mpart)
{
    __shared__ _Float16 xls[256][72];   // 36,864 B : X rows (c), 64 k per chunk
    __shared__ _Float16 wls[32][72];    //  4,608 B : W rows (r), 64 k per chunk
    int t = threadIdx.x;
    int b = blockIdx.x >> 4, seg = blockIdx.x & 15;
    int xys0 = seg * 256;
    int lane = t & 63;
    int wid = __builtin_amdgcn_readfirstlane(t >> 6);   // 0..7
    int r16 = lane & 15, g = lane >> 4;
    int n0 = wid * 32;

    // staging coords
    int sc = t >> 1, shalf = t & 1;                 // x: row sc, 32-col half
    int wr = t >> 3, wco = (t & 7) * 8;             // w: row wr (t<256 only)
    float wm = 0.f, winv = 0.f;
    if (t < 256 && wr < 16) {
        wm   = stats[(b * 16 + wr) * 2 + 0];
        winv = stats[(b * 16 + wr) * 2 + 1];
    }

    f32x4 acc00 = {0.f,0.f,0.f,0.f}, acc01 = {0.f,0.f,0.f,0.f};
    f32x4 acc10 = {0.f,0.f,0.f,0.f}, acc11 = {0.f,0.f,0.f,0.f};

    for (int ch = 0; ch < 4; ++ch) {
        int kbase = xys0 + ch * 64;
        __syncthreads();                            // prev chunk's reads done
        {   // stage X: 256 rows x 64 k  (thread: row sc, cols shalf*32..+31)
            const float* xp = x + ((size_t)b * C_ + sc) * WH + kbase + shalf * 32;
#pragma unroll
            for (int j = 0; j < 4; ++j) {
                float4 u  = *(const float4*)(xp + j * 8);
                float4 u2 = *(const float4*)(xp + j * 8 + 4);
                f16x8 o;
                o[0] = (_Float16)u.x;  o[1] = (_Float16)u.y;
                o[2] = (_Float16)u.z;  o[3] = (_Float16)u.w;
                o[4] = (_Float16)u2.x; o[5] = (_Float16)u2.y;
                o[6] = (_Float16)u2.z; o[7] = (_Float16)u2.w;
                *(f16x8*)&xls[sc][shalf * 32 + j * 8] = o;
            }
        }
        if (t < 256) {  // stage W: rows 0..15 = sm(kkbn), 16..31 = Wt
            f16x8 o;
            if (wr < 16) {
                const float* src = kkbn + ((size_t)b * 16 + wr) * WH + kbase + wco;
                float4 u  = *(const float4*)(src);
                float4 u2 = *(const float4*)(src + 4);
                o[0] = (_Float16)(__expf(u.x  - wm) * winv);
                o[1] = (_Float16)(__expf(u.y  - wm) * winv);
                o[2] = (_Float16)(__expf(u.z  - wm) * winv);
                o[3] = (_Float16)(__expf(u.w  - wm) * winv);
                o[4] = (_Float16)(__expf(u2.x - wm) * winv);
                o[5] = (_Float16)(__expf(u2.y - wm) * winv);
                o[6] = (_Float16)(__expf(u2.z - wm) * winv);
                o[7] = (_Float16)(__expf(u2.w - wm) * winv);
            } else {
                const float* src = Wt + (size_t)(wr - 16) * WH + kbase + wco;
                float4 u  = *(const float4*)(src);
                float4 u2 = *(const float4*)(src + 4);
                o[0] = (_Float16)u.x;  o[1] = (_Float16)u.y;
                o[2] = (_Float16)u.z;  o[3] = (_Float16)u.w;
                o[4] = (_Float16)u2.x; o[5] = (_Float16)u2.y;
                o[6] = (_Float16)u2.z; o[7] = (_Float16)u2.w;
            }
            *(f16x8*)&wls[wr][wco] = o;
        }
        __syncthreads();                            // tile visible
#pragma unroll
        for (int s = 0; s < 2; ++s) {
            int koff = s * 32 + g * 8;
            f16x8 A0 = *(const f16x8*)&wls[r16     ][koff];
            f16x8 A1 = *(const f16x8*)&wls[16 + r16][koff];
            f16x8 B0 = *(const f16x8*)&xls[n0 + r16     ][koff];
            f16x8 B1 = *(const f16x8*)&xls[n0 + 16 + r16][koff];
            acc00 = __builtin_amdgcn_mfma_f32_16x16x32_f16(A0, B0, acc00, 0, 0, 0);
            acc01 = __builtin_amdgcn_mfma_f32_16x16x32_f16(A0, B1, acc01, 0, 0, 0);
            acc10 = __builtin_amdgcn_mfma_f32_16x16x32_f16(A1, B0, acc10, 0, 0, 0);
            acc11 = __builtin_amdgcn_mfma_f32_16x16x32_f16(A1, B1, acc11, 0, 0, 0);
        }
    }

    // D layout: row = mt*16 + g*4 + reg, col = n0 + nt*16 + r16
    float* mp = Mpart + (size_t)(b * 16 + seg) * 8192;
    int colA = n0 + r16, colB = n0 + 16 + r16;
    int row0 = g * 4, row1 = 16 + g * 4;
#pragma unroll
    for (int rr = 0; rr < 4; ++rr) {
        mp[(row0 + rr) * 256 + colA] = acc00[rr];
        mp[(row0 + rr) * 256 + colB] = acc01[rr];
        mp[(row1 + rr) * 256 + colA] = acc10[rr];
        mp[(row1 + rr) * 256 + colB] = acc11[rr];
    }
}

// ---- lambda[b,hk,v] = sum_c v_w[h,v,c] * (U+T)[b,hk,c]. One block per (b,hk). ----
__global__ __launch_bounds__(256) void lam_kernel(
    const float* __restrict__ Mpart, const float* __restrict__ vw,
    float* __restrict__ lam)
{
    __shared__ float msum[256];
    __shared__ float vls[64][68];
    __shared__ float psum[4][64];
    int t = threadIdx.x;
    int b = blockIdx.x >> 4, hk = blockIdx.x & 15, h = hk >> 2;

    {
        const float* mp = Mpart + (size_t)b * 16 * 8192 + t;
        float s = 0.f;
        for (int seg = 0; seg < 16; ++seg) {
            const float* m2 = mp + (size_t)seg * 8192;
            s += m2[hk * 256] + m2[(16 + hk) * 256];
        }
        msum[t] = s;
    }

    int v = t & 63, cq = t >> 6;
    float acc = 0.f;
    const float* vwh = vw + (size_t)h * 64 * 256;
    for (int ch = 0; ch < 4; ++ch) {
        __syncthreads();
#pragma unroll
        for (int k = 0; k < 4; ++k) {
            int e = t + k * 256;
            int vv = e >> 4, c4 = (e & 15) * 4;
            *(float4*)&vls[vv][c4] = *(const float4*)(vwh + (size_t)vv * 256 + ch * 64 + c4);
        }
        __syncthreads();
#pragma unroll
        for (int i4 = 0; i4 < 4; ++i4) {
            float4 a  = *(const float4*)&vls[v][cq * 16 + i4 * 4];
            float4 m4 = *(const float4*)&msum[ch * 64 + cq * 16 + i4 * 4];
            acc += a.x * m4.x + a.y * m4.y + a.z * m4.z + a.w * m4.w;
        }
    }
    psum[cq][v] = acc;
    __syncthreads();
    if (t < 64)
        lam[((size_t)b * 16 + hk) * 64 + t] =
            psum[0][t] + psum[1][t] + psum[2][t] + psum[3][t];
}

// ---- out[b, h*64+v, xy] = sum_k qbn[b,hk,xy] * lam[b,hk,v]. ----
__global__ __launch_bounds__(256) void out_kernel(
    const float* __restrict__ qbn, const float* __restrict__ lam,
    float* __restrict__ out)
{
    int t = threadIdx.x;
    int b = blockIdx.x >> 4, s = blockIdx.x & 15;
    int h = s >> 2, qc = s & 3;
    int xy = qc * 1024 + t * 4;
    float4 q0 = *(const float4*)(qbn + ((size_t)b * 16 + h * 4 + 0) * WH + xy);
    float4 q1 = *(const float4*)(qbn + ((size_t)b * 16 + h * 4 + 1) * WH + xy);
    float4 q2 = *(const float4*)(qbn + ((size_t)b * 16 + h * 4 + 2) * WH + xy);
    float4 q3 = *(const float4*)(qbn + ((size_t)b * 16 + h * 4 + 3) * WH + xy);
    const float* lb = lam + (size_t)b * 1024 + (size_t)h * 256;
    float* ob = out + ((size_t)b * 256 + (size_t)h * 64) * WH + xy;
#pragma unroll 8
    for (int v = 0; v < 64; ++v) {
        float l0 = lb[v], l1 = lb[64 + v], l2 = lb[128 + v], l3 = lb[192 + v];
        float4 o;
        o.x = q0.x*l0 + q1.x*l1 + q2.x*l2 + q3.x*l3;
        o.y = q0.y*l0 + q1.y*l1 + q2.y*l2 + q3.y*l3;
        o.z = q0.z*l0 + q1.z*l1 + q2.z*l2 + q3.z*l3;
        o.w = q0.w*l0 + q1.w*l1 + q2.w*l2 + q3.w*l3;
        *(float4*)(ob + (size_t)v * WH) = o;
    }
}

extern "C" void kernel_launch(void* const* d_in, const int* in_sizes, int n_in,
                              void* d_out, int out_size, void* d_ws, size_t ws_size,
                              hipStream_t stream)
{
    const float* x   = (const float*)d_in[0];
    const float* qw  = (const float*)d_in[1];
    const float* qg  = (const float*)d_in[2];
    const float* qb  = (const float*)d_in[3];
    const float* qm  = (const float*)d_in[4];
    const float* qv  = (const float*)d_in[5];
    const float* kw  = (const float*)d_in[6];
    const float* kg  = (const float*)d_in[7];
    const float* kb  = (const float*)d_in[8];
    const float* km  = (const float*)d_in[9];
    const float* kv  = (const float*)d_in[10];
    const float* vw  = (const float*)d_in[11];
    const float* emb = (const float*)d_in[12];

    float* ws    = (float*)d_ws;
    float* qbn   = ws;
    float* kkbn  = ws + 1048576;
    float* stats = ws + 2097152;
    float* Wt    = ws + 2097664;
    float* Mpart = ws + 2163200;
    float* pstats = Mpart;            // alias: proj writes, wtcomb reads, ut overwrites
    float* lam   = ws + 4260352;
    float* out   = (float*)d_out;

    hipLaunchKernelGGL(proj_kernel,  dim3(256), dim3(512), 0, stream,
                       x, qw, kw, qg, qb, qm, qv, kg, kb, km, kv, qbn, kkbn, pstats);
    hipLaunchKernelGGL(wtcomb_kernel, dim3(65), dim3(256), 0, stream, emb, pstats, Wt, stats);
    hipLaunchKernelGGL(ut_kernel,    dim3(256), dim3(512), 0, stream,
                       x, kkbn, stats, Wt, Mpart);
    hipLaunchKernelGGL(lam_kernel,   dim3(256), dim3(256), 0, stream, Mpart, vw, lam);
    hipLaunchKernelGGL(out_kernel,   dim3(256), dim3(256), 0, stream, qbn, lam, out);
}

// Round 5
// 74.477 us; speedup vs baseline: 5.9646x; 1.1637x over previous
//
#include <hip/hip_runtime.h>
#include <math.h>

#define C_   256
#define WH   4096

typedef _Float16 f16x8 __attribute__((ext_vector_type(8)));
typedef float    f32x4 __attribute__((ext_vector_type(4)));

// ---------------- workspace layout (floats) ----------------
// qbn   : [16][16][4096]          @ 0          (1,048,576)
// kkbn  : [16][16][4096]          @ 1,048,576  (1,048,576)
// pstats: [256 rows][16 chunk][2] @ 2,097,152  (8,192)
// Wt    : [16][4096]              @ 2,105,344  (65,536)
// Mpart : [16][32 part][32][256]  @ 2,170,880  (4,194,304)
// lam   : [16][16][64]            @ 6,365,184  (16,384)

// ---- q/k 1x1 projections + BN + per-chunk softmax partials (blocks 0..255)
//      + Wt generation (blocks 256..319). ----
__global__ __launch_bounds__(512) void proj_kernel(
    const float* __restrict__ x,
    const float* __restrict__ qw, const float* __restrict__ kw,
    const float* __restrict__ qg, const float* __restrict__ qb,
    const float* __restrict__ qm, const float* __restrict__ qv,
    const float* __restrict__ kg, const float* __restrict__ kb,
    const float* __restrict__ km, const float* __restrict__ kv,
    const float* __restrict__ emb,
    float* __restrict__ qbn, float* __restrict__ kkbn,
    float* __restrict__ pstats, float* __restrict__ Wt)
{
    if (blockIdx.x >= 256) {
        // ---- Wt: summed spatial weight of the positional conv ----
        int wb = blockIdx.x - 256;
        int hk = wb >> 2, quarter = wb & 3;
        int h = hk >> 2, k = hk & 3;
        const float* e = emb + (size_t)(k * 4 + h) * 529;   // emb[k][h][0][0][i][j]
        __shared__ float colsum[23][64];
        for (int t2 = threadIdx.x; t2 < 23 * 64; t2 += 512) {
            int i = t2 / 64, q = t2 % 64;
            int jlo = max(0, q - 52), jhi = min(22, q + 11);
            float s = 0.f;
            for (int j = jlo; j <= jhi; ++j) s += e[i * 23 + j];
            colsum[i][q] = s;
        }
        __syncthreads();
        for (int tt = threadIdx.x; tt < 1024; tt += 512) {
            int t2 = quarter * 1024 + tt;
            int p = t2 >> 6, q = t2 & 63;
            int ilo = max(0, p - 52), ihi = min(22, p + 11);
            float s = 0.f;
            for (int i = ilo; i <= ihi; ++i) s += colsum[i][q];
            Wt[(size_t)hk * WH + t2] = s;
        }
        return;
    }

    int t = threadIdx.x;
    int b = blockIdx.x >> 4, chunk = blockIdx.x & 15;
    int lane = t & 63;
    int og = __builtin_amdgcn_readfirstlane(t >> 6);   // 0..7, wave-uniform
    int isK = og >> 2;
    int o4 = (og & 3) * 4;
    int xy = chunk * 256 + lane * 4;

    const float* wsrc = isK ? kw : qw;
    const float* w0 = wsrc + (size_t)(o4 + 0) * 256;
    const float* w1 = wsrc + (size_t)(o4 + 1) * 256;
    const float* w2 = wsrc + (size_t)(o4 + 2) * 256;
    const float* w3 = wsrc + (size_t)(o4 + 3) * 256;

    float4 a0 = {0,0,0,0}, a1 = {0,0,0,0}, a2 = {0,0,0,0}, a3 = {0,0,0,0};
    const float* xb = x + (size_t)b * C_ * WH + xy;
#pragma unroll 8
    for (int c = 0; c < 256; ++c) {
        float4 xv = *(const float4*)(xb + (size_t)c * WH);
        float f0 = w0[c], f1 = w1[c], f2 = w2[c], f3 = w3[c];
        a0.x += xv.x*f0; a0.y += xv.y*f0; a0.z += xv.z*f0; a0.w += xv.w*f0;
        a1.x += xv.x*f1; a1.y += xv.y*f1; a1.z += xv.z*f1; a1.w += xv.w*f1;
        a2.x += xv.x*f2; a2.y += xv.y*f2; a2.z += xv.z*f2; a2.w += xv.w*f2;
        a3.x += xv.x*f3; a3.y += xv.y*f3; a3.z += xv.z*f3; a3.w += xv.w*f3;
    }
    float4 acc4[4] = {a0, a1, a2, a3};

    if (!isK) {
#pragma unroll
        for (int i = 0; i < 4; ++i) {
            int hk = o4 + i;
            float s  = qg[hk] * rsqrtf(qv[hk] + 1e-5f);
            float tq = qb[hk] - qm[hk] * s;
            float4 a = acc4[i], o;
            o.x = a.x * s + tq; o.y = a.y * s + tq;
            o.z = a.z * s + tq; o.w = a.w * s + tq;
            *(float4*)(qbn + ((size_t)b * 16 + hk) * WH + xy) = o;
        }
    } else {
#pragma unroll
        for (int i = 0; i < 4; ++i) {
            int hk = o4 + i;
            float s2 = kg[hk] * rsqrtf(kv[hk] + 1e-5f);
            float tk = kb[hk] - km[hk] * s2;
            float4 a = acc4[i], o;
            o.x = a.x * s2 + tk; o.y = a.y * s2 + tk;
            o.z = a.z * s2 + tk; o.w = a.w * s2 + tk;
            *(float4*)(kkbn + ((size_t)b * 16 + hk) * WH + xy) = o;
            float m = fmaxf(fmaxf(o.x, o.y), fmaxf(o.z, o.w));
#pragma unroll
            for (int off = 32; off; off >>= 1) m = fmaxf(m, __shfl_xor(m, off, 64));
            float e = __expf(o.x - m) + __expf(o.y - m) + __expf(o.z - m) + __expf(o.w - m);
#pragma unroll
            for (int off = 32; off; off >>= 1) e += __shfl_xor(e, off, 64);
            if (lane == 0) {
                float* ps = pstats + ((size_t)(b * 16 + hk) * 16 + chunk) * 2;
                ps[0] = m; ps[1] = e;
            }
        }
    }
}

// ---- U/T contractions via fp16 MFMA (fp32 accumulate).
// Grid 512 = (b, s5 of 128 xy) -> 2 blocks/CU so staging of one block
// overlaps MFMA of the other. Softmax stats combined inline from pstats.
// Per block: D[32 r][256 c] = sum_{xy in 128} W[r][xy] * X[c][xy],
// K = 128 (2 chunks x 64). Layouts identical to the proven round-4 kernel. ----
__global__ __launch_bounds__(512) void ut_kernel(
    const float* __restrict__ x, const float* __restrict__ kkbn,
    const float* __restrict__ pstats, const float* __restrict__ Wt,
    float* __restrict__ Mpart)
{
    __shared__ _Float16 xls[256][72];   // 36,864 B : X rows (c), 64 k per chunk
    __shared__ _Float16 wls[32][72];    //  4,608 B : W rows (r), 64 k per chunk
    __shared__ float st[32];            // M, 1/S per sm row
    int t = threadIdx.x;
    int b = blockIdx.x >> 5, s5 = blockIdx.x & 31;
    int xys0 = s5 * 128;
    int lane = t & 63;
    int wid = __builtin_amdgcn_readfirstlane(t >> 6);   // 0..7
    int r16 = lane & 15, g = lane >> 4;
    int n0 = wid * 32;

    // ---- inline softmax-stats combine: thread r<16 handles row r ----
    if (t < 16) {
        const float* ps = pstats + (size_t)(b * 16 + t) * 32;
        float M = ps[0];
#pragma unroll
        for (int ch = 1; ch < 16; ++ch) M = fmaxf(M, ps[ch * 2]);
        float S = 0.f;
#pragma unroll
        for (int ch = 0; ch < 16; ++ch) S += ps[ch * 2 + 1] * __expf(ps[ch * 2] - M);
        st[2 * t]     = M;
        st[2 * t + 1] = 1.f / S;
    }

    // staging coords
    int sc = t >> 1, shalf = t & 1;                 // x: row sc, 32-col half
    int wr = t >> 3, wco = (t & 7) * 8;             // w: row wr (t<256 only)

    f32x4 acc00 = {0.f,0.f,0.f,0.f}, acc01 = {0.f,0.f,0.f,0.f};
    f32x4 acc10 = {0.f,0.f,0.f,0.f}, acc11 = {0.f,0.f,0.f,0.f};

    for (int ch = 0; ch < 2; ++ch) {
        int kbase = xys0 + ch * 64;
        __syncthreads();                            // st[] visible / prev reads done
        {   // stage X: 256 rows x 64 k  (thread: row sc, cols shalf*32..+31)
            const float* xp = x + ((size_t)b * C_ + sc) * WH + kbase + shalf * 32;
#pragma unroll
            for (int j = 0; j < 4; ++j) {
                float4 u  = *(const float4*)(xp + j * 8);
                float4 u2 = *(const float4*)(xp + j * 8 + 4);
                f16x8 o;
                o[0] = (_Float16)u.x;  o[1] = (_Float16)u.y;
                o[2] = (_Float16)u.z;  o[3] = (_Float16)u.w;
                o[4] = (_Float16)u2.x; o[5] = (_Float16)u2.y;
                o[6] = (_Float16)u2.z; o[7] = (_Float16)u2.w;
                *(f16x8*)&xls[sc][shalf * 32 + j * 8] = o;
            }
        }
        if (t < 256) {  // stage W: rows 0..15 = sm(kkbn), 16..31 = Wt
            f16x8 o;
            if (wr < 16) {
                float wm   = st[2 * wr];
                float winv = st[2 * wr + 1];
                const float* src = kkbn + ((size_t)b * 16 + wr) * WH + kbase + wco;
                float4 u  = *(const float4*)(src);
                float4 u2 = *(const float4*)(src + 4);
                o[0] = (_Float16)(__expf(u.x  - wm) * winv);
                o[1] = (_Float16)(__expf(u.y  - wm) * winv);
                o[2] = (_Float16)(__expf(u.z  - wm) * winv);
                o[3] = (_Float16)(__expf(u.w  - wm) * winv);
                o[4] = (_Float16)(__expf(u2.x - wm) * winv);
                o[5] = (_Float16)(__expf(u2.y - wm) * winv);
                o[6] = (_Float16)(__expf(u2.z - wm) * winv);
                o[7] = (_Float16)(__expf(u2.w - wm) * winv);
            } else {
                const float* src = Wt + (size_t)(wr - 16) * WH + kbase + wco;
                float4 u  = *(const float4*)(src);
                float4 u2 = *(const float4*)(src + 4);
                o[0] = (_Float16)u.x;  o[1] = (_Float16)u.y;
                o[2] = (_Float16)u.z;  o[3] = (_Float16)u.w;
                o[4] = (_Float16)u2.x; o[5] = (_Float16)u2.y;
                o[6] = (_Float16)u2.z; o[7] = (_Float16)u2.w;
            }
            *(f16x8*)&wls[wr][wco] = o;
        }
        __syncthreads();                            // tile visible
#pragma unroll
        for (int s = 0; s < 2; ++s) {
            int koff = s * 32 + g * 8;
            f16x8 A0 = *(const f16x8*)&wls[r16     ][koff];
            f16x8 A1 = *(const f16x8*)&wls[16 + r16][koff];
            f16x8 B0 = *(const f16x8*)&xls[n0 + r16     ][koff];
            f16x8 B1 = *(const f16x8*)&xls[n0 + 16 + r16][koff];
            acc00 = __builtin_amdgcn_mfma_f32_16x16x32_f16(A0, B0, acc00, 0, 0, 0);
            acc01 = __builtin_amdgcn_mfma_f32_16x16x32_f16(A0, B1, acc01, 0, 0, 0);
            acc10 = __builtin_amdgcn_mfma_f32_16x16x32_f16(A1, B0, acc10, 0, 0, 0);
            acc11 = __builtin_amdgcn_mfma_f32_16x16x32_f16(A1, B1, acc11, 0, 0, 0);
        }
    }

    // D layout: row = mt*16 + g*4 + reg, col = n0 + nt*16 + r16
    float* mp = Mpart + (size_t)(b * 32 + s5) * 8192;
    int colA = n0 + r16, colB = n0 + 16 + r16;
    int row0 = g * 4, row1 = 16 + g * 4;
#pragma unroll
    for (int rr = 0; rr < 4; ++rr) {
        mp[(row0 + rr) * 256 + colA] = acc00[rr];
        mp[(row0 + rr) * 256 + colB] = acc01[rr];
        mp[(row1 + rr) * 256 + colA] = acc10[rr];
        mp[(row1 + rr) * 256 + colB] = acc11[rr];
    }
}

// ---- lambda[b,hk,v] = sum_c v_w[h,v,c] * (U+T)[b,hk,c]. One block per (b,hk). ----
__global__ __launch_bounds__(256) void lam_kernel(
    const float* __restrict__ Mpart, const float* __restrict__ vw,
    float* __restrict__ lam)
{
    __shared__ float msum[256];
    __shared__ float vls[64][68];
    __shared__ float psum[4][64];
    int t = threadIdx.x;
    int b = blockIdx.x >> 4, hk = blockIdx.x & 15, h = hk >> 2;

    {
        const float* mp = Mpart + (size_t)b * 32 * 8192 + t;
        float s = 0.f;
        for (int seg = 0; seg < 32; ++seg) {
            const float* m2 = mp + (size_t)seg * 8192;
            s += m2[hk * 256] + m2[(16 + hk) * 256];
        }
        msum[t] = s;
    }

    int v = t & 63, cq = t >> 6;
    float acc = 0.f;
    const float* vwh = vw + (size_t)h * 64 * 256;
    for (int ch = 0; ch < 4; ++ch) {
        __syncthreads();
#pragma unroll
        for (int k = 0; k < 4; ++k) {
            int e = t + k * 256;
            int vv = e >> 4, c4 = (e & 15) * 4;
            *(float4*)&vls[vv][c4] = *(const float4*)(vwh + (size_t)vv * 256 + ch * 64 + c4);
        }
        __syncthreads();
#pragma unroll
        for (int i4 = 0; i4 < 4; ++i4) {
            float4 a  = *(const float4*)&vls[v][cq * 16 + i4 * 4];
            float4 m4 = *(const float4*)&msum[ch * 64 + cq * 16 + i4 * 4];
            acc += a.x * m4.x + a.y * m4.y + a.z * m4.z + a.w * m4.w;
        }
    }
    psum[cq][v] = acc;
    __syncthreads();
    if (t < 64)
        lam[((size_t)b * 16 + hk) * 64 + t] =
            psum[0][t] + psum[1][t] + psum[2][t] + psum[3][t];
}

// ---- out[b, h*64+v, xy] = sum_k qbn[b,hk,xy] * lam[b,hk,v]. ----
__global__ __launch_bounds__(256) void out_kernel(
    const float* __restrict__ qbn, const float* __restrict__ lam,
    float* __restrict__ out)
{
    int t = threadIdx.x;
    int b = blockIdx.x >> 4, s = blockIdx.x & 15;
    int h = s >> 2, qc = s & 3;
    int xy = qc * 1024 + t * 4;
    float4 q0 = *(const float4*)(qbn + ((size_t)b * 16 + h * 4 + 0) * WH + xy);
    float4 q1 = *(const float4*)(qbn + ((size_t)b * 16 + h * 4 + 1) * WH + xy);
    float4 q2 = *(const float4*)(qbn + ((size_t)b * 16 + h * 4 + 2) * WH + xy);
    float4 q3 = *(const float4*)(qbn + ((size_t)b * 16 + h * 4 + 3) * WH + xy);
    const float* lb = lam + (size_t)b * 1024 + (size_t)h * 256;
    float* ob = out + ((size_t)b * 256 + (size_t)h * 64) * WH + xy;
#pragma unroll 8
    for (int v = 0; v < 64; ++v) {
        float l0 = lb[v], l1 = lb[64 + v], l2 = lb[128 + v], l3 = lb[192 + v];
        float4 o;
        o.x = q0.x*l0 + q1.x*l1 + q2.x*l2 + q3.x*l3;
        o.y = q0.y*l0 + q1.y*l1 + q2.y*l2 + q3.y*l3;
        o.z = q0.z*l0 + q1.z*l1 + q2.z*l2 + q3.z*l3;
        o.w = q0.w*l0 + q1.w*l1 + q2.w*l2 + q3.w*l3;
        *(float4*)(ob + (size_t)v * WH) = o;
    }
}

extern "C" void kernel_launch(void* const* d_in, const int* in_sizes, int n_in,
                              void* d_out, int out_size, void* d_ws, size_t ws_size,
                              hipStream_t stream)
{
    const float* x   = (const float*)d_in[0];
    const float* qw  = (const float*)d_in[1];
    const float* qg  = (const float*)d_in[2];
    const float* qb  = (const float*)d_in[3];
    const float* qm  = (const float*)d_in[4];
    const float* qv  = (const float*)d_in[5];
    const float* kw  = (const float*)d_in[6];
    const float* kg  = (const float*)d_in[7];
    const float* kb  = (const float*)d_in[8];
    const float* km  = (const float*)d_in[9];
    const float* kv  = (const float*)d_in[10];
    const float* vw  = (const float*)d_in[11];
    const float* emb = (const float*)d_in[12];

    float* ws     = (float*)d_ws;
    float* qbn    = ws;
    float* kkbn   = ws + 1048576;
    float* pstats = ws + 2097152;
    float* Wt     = ws + 2105344;
    float* Mpart  = ws + 2170880;
    float* lam    = ws + 6365184;
    float* out    = (float*)d_out;

    hipLaunchKernelGGL(proj_kernel,  dim3(320), dim3(512), 0, stream,
                       x, qw, kw, qg, qb, qm, qv, kg, kb, km, kv, emb,
                       qbn, kkbn, pstats, Wt);
    hipLaunchKernelGGL(ut_kernel,    dim3(512), dim3(512), 0, stream,
                       x, kkbn, pstats, Wt, Mpart);
    hipLaunchKernelGGL(lam_kernel,   dim3(256), dim3(256), 0, stream, Mpart, vw, lam);
    hipLaunchKernelGGL(out_kernel,   dim3(256), dim3(256), 0, stream, qbn, lam, out);
}